// Round 5
// baseline (430.053 us; speedup 1.0000x reference)
//
#include <hip/hip_runtime.h>
#include <hip/hip_bf16.h>
#include <stdint.h>

typedef __attribute__((ext_vector_type(8))) short short8;
typedef __attribute__((ext_vector_type(16))) float floatx16;
typedef unsigned short u16;

#define IN_DIM  1024
#define OUT_DIM 1024
#define NG      11            // spline bases per channel
#define GK      12            // + silu slot
#define KDIM    (IN_DIM * GK) // 12288
#define TOKENS  8192
#define FBK     48            // fused tile K elems = 4 channels x 12 slots (3 k-steps of 16)
#define FROW    56            // LDS row stride elems: 7 granules (6 data + 1 pad-dup)
#define FBUF    (256 * FROW)  // 14336 u16 per operand-parity buffer (28672 B)
#define FOPS    4             // B DMA ops per wave per tile (32 total: 28 real + 4 dup)

__device__ __forceinline__ u16 f2bf(float f) {
  uint32_t u = __float_as_uint(f);
  uint32_t r = (u + 0x7fffu + ((u >> 16) & 1u)) >> 16;  // RNE
  return (u16)r;
}

// ---------------- pack Wt: bf16 [OUT_DIM][KDIM] (unchanged, verified)
__global__ __launch_bounds__(256) void pack_wt_kernel(
    const float* __restrict__ coeff, const float* __restrict__ sb,
    const float* __restrict__ ss_p, u16* __restrict__ Wt)
{
  __shared__ float cf[256 * NG];
  __shared__ __align__(16) u16 st[256 * GK];
  const int tid = threadIdx.x;
  const int b   = blockIdx.x;
  const int o   = b >> 2;
  const int i0  = (b & 3) * 256;
  const float* cbase = coeff + (size_t)o * (IN_DIM * NG) + (size_t)i0 * NG;
#pragma unroll
  for (int p = 0; p < NG; ++p) cf[p * 256 + tid] = cbase[p * 256 + tid];
  const float ss  = ss_p[0];
  const float sbv = sb[(size_t)o * IN_DIM + i0 + tid];
  __syncthreads();
  const float* cp = cf + tid * NG;
  u16 h[GK];
#pragma unroll
  for (int g = 0; g < NG; ++g) h[g] = f2bf(cp[g] * ss);
  h[NG] = f2bf(sbv);
  uint64_t V0 = (uint64_t)h[0] | ((uint64_t)h[1] << 16) | ((uint64_t)h[2] << 32) | ((uint64_t)h[3] << 48);
  uint64_t V1 = (uint64_t)h[4] | ((uint64_t)h[5] << 16) | ((uint64_t)h[6] << 32) | ((uint64_t)h[7] << 48);
  uint64_t V2 = (uint64_t)h[8] | ((uint64_t)h[9] << 16) | ((uint64_t)h[10] << 32) | ((uint64_t)h[11] << 48);
  uint64_t* sp = (uint64_t*)(st + tid * GK);
  sp[0] = V0; sp[1] = V1; sp[2] = V2;
  __syncthreads();
  const uint4* src = (const uint4*)st;
  uint4* dst = (uint4*)(Wt + (size_t)b * (256 * GK));
  dst[tid] = src[tid];
  if (tid < 128) dst[256 + tid] = src[256 + tid];
}

// Closed-form cubic B-spline + silu -> 3 u64 (verified, absmax 0.125)
__device__ __forceinline__ void expand_regs(float x, float g0, float inv_h,
                                            uint64_t& V0, uint64_t& V1, uint64_t& V2)
{
  float t  = (x - g0) * inv_h;
  float fc = floorf(t);
  int   c  = (int)fc;
  float u  = t - fc;
  float u2 = u * u;
  float w1 = 1.0f - u;
  float b0 = (w1 * w1 * w1) * (1.0f / 6.0f);
  float b1 = (0.5f * u - 1.0f) * u2 + (2.0f / 3.0f);
  float b2 = ((-0.5f * u + 0.5f) * u + 0.5f) * u + (1.0f / 6.0f);
  float b3 = (u2 * u) * (1.0f / 6.0f);
  float sil = x / (1.0f + __expf(-x));

  uint64_t P = (uint64_t)f2bf(b0) | ((uint64_t)f2bf(b1) << 16)
             | ((uint64_t)f2bf(b2) << 32) | ((uint64_t)f2bf(b3) << 48);
  int  k  = c - 3;
  bool cv = (c >= 0) && (c <= 13);
  int  kneg = (k < 0) ? -k : 0;
  uint64_t Pc = cv ? (P >> (16 * kneg)) : 0ull;
  uint32_t sh = (uint32_t)(16 * ((k < 0) ? 0 : k));

  V0 = (sh < 64)  ? (Pc << (sh & 63)) : 0ull;
  V1 = (sh == 0)  ? 0ull :
       (sh < 64)  ? (Pc >> ((64 - sh) & 63)) :
       (sh < 128) ? (Pc << ((sh - 64) & 63)) : 0ull;
  V2 = (sh <= 64) ? 0ull :
       (sh < 128) ? (Pc >> ((128 - sh) & 63)) :
                    (Pc << ((sh - 128) & 63));
  V2 = (V2 & 0x0000FFFFFFFFFFFFull) | ((uint64_t)f2bf(sil) << 48);
}

__device__ __forceinline__ void async16(const u16* g, u16* l) {
  __builtin_amdgcn_global_load_lds(
      (const __attribute__((address_space(1))) uint32_t*)g,
      (__attribute__((address_space(3))) uint32_t*)l,
      16, 0, 0);
}

// expand 2 channels -> 6 u64
__device__ __forceinline__ void expand2(float2 xv, float g0, float inv_h, uint64_t e[6]) {
  expand_regs(xv.x, g0, inv_h, e[0], e[1], e[2]);
  expand_regs(xv.y, g0, inv_h, e[3], e[4], e[5]);
}

// write 6 u64 = 48 B as 3 uint4 into A buffer at element offset awoff (16B aligned)
__device__ __forceinline__ void write_ev(u16* abase, int awoff, const uint64_t e[6]) {
  uint4* w = (uint4*)(abase + awoff);
  uint4 w0, w1, w2;
  w0.x = (uint32_t)e[0]; w0.y = (uint32_t)(e[0] >> 32);
  w0.z = (uint32_t)e[1]; w0.w = (uint32_t)(e[1] >> 32);
  w1.x = (uint32_t)e[2]; w1.y = (uint32_t)(e[2] >> 32);
  w1.z = (uint32_t)e[3]; w1.w = (uint32_t)(e[3] >> 32);
  w2.x = (uint32_t)e[4]; w2.y = (uint32_t)(e[4] >> 32);
  w2.z = (uint32_t)e[5]; w2.w = (uint32_t)(e[5] >> 32);
  w[0] = w0; w[1] = w1; w[2] = w2;
}

// ---------------- GEMM v5: fused expansion + 256x256 tile + counted-vmcnt pipeline.
// A is expanded in-kernel (VALU, hides under MFMA) and ds_written to LDS;
// B is DMA'd with the round-4 counted-vmcnt scheme. Kills the 201MB Aexp
// stream (round-4 GEMM was LLC-BW-bound at ~8.4 TB/s: 73.7KB/tile / 5400cyc)
// and the standalone expand kernel (~84us).
// BK=48 (4 ch x 12), rows = 7 granules (6 data + 1 pad-dup; stride 112B ->
// bank-rotation, same class as measured-0-conflict GR=9). Dbuf A+B = 112KB.
// Uniform vmem ops/wave (round-3 lesson): 4 B-DMA + 1 x-prefetch = 5 ->
// vmcnt(5) steady / vmcnt(4) in x-tail / vmcnt(0) at drain.
// bm = r&31 -> bid%8 = bm%8: 4 bm-blocks sharing a B strip co-run on one XCD
// (B re-reads L2-absorbed; X is L3-resident).
__global__ __launch_bounds__(512, 2) void gemm_fused2_kernel(
    const float* __restrict__ X, const float* __restrict__ grid,
    const u16* __restrict__ Wt, float* __restrict__ out, float* __restrict__ part,
    int k_iters)   // tiles of 4 channels per split
{
  __shared__ __align__(16) u16 S[4 * FBUF];   // A:p0,p1  B:p0,p1 = 114688 B

  const int tid  = threadIdx.x;
  const int lane = tid & 63;
  const int wave = tid >> 6;              // 0..7
  const int s    = blockIdx.x >> 7;       // 128 blocks per K-split
  const int r    = blockIdx.x & 127;
  const int bm   = r & 31;
  const int bn   = r >> 5;
  const int wm   = (wave >> 2) * 128;     // 2 M-warps
  const int wn   = (wave & 3) * 64;       // 4 N-warps
  const int l31  = lane & 31;
  const int g8   = lane >> 5;

  const float g0    = grid[0];
  const float inv_h = 1.0f / (grid[1] - grid[0]);

  floatx16 acc[4][2];
#pragma unroll
  for (int a = 0; a < 4; ++a)
#pragma unroll
    for (int b = 0; b < 2; ++b)
#pragma unroll
      for (int rr = 0; rr < 16; ++rr) acc[a][b][rr] = 0.f;

  // B DMA setup: op o = wave + 8j (j<4, o<32), oc = min(o,27) -> dup tail
  // keeps ops/wave uniform. lane: gidx = oc*64+lane; row = gidx/7;
  // slot = gidx%7; slot 6 = pad -> harmless dup of slot 0.
  const int kb = s * k_iters * FBK;       // u16 offset into Wt row
  const u16* bsrc[FOPS]; int bdof[FOPS];
#pragma unroll
  for (int j = 0; j < FOPS; ++j) {
    int o  = wave + 8 * j;
    int oc = (o < 28) ? o : 27;
    int gidx = oc * 64 + lane;
    int row  = gidx / 7;
    int sl   = gidx - row * 7;
    int c6   = (sl == 6) ? 0 : sl;
    bsrc[j] = Wt + (size_t)(bn * 256 + row) * KDIM + kb + c6 * 8;
    bdof[j] = oc * 512;                   // 64 granules = 1024 B per op
  }

  // A expansion setup: thread -> (row = tid>>1, channel pair cp = (tid&1)*2)
  const int arow  = tid >> 1;
  const int cp    = (tid & 1) * 2;
  const float* xp = X + (size_t)(bm * 256 + arow) * IN_DIM + s * (k_iters * 4) + cp;
  const int awoff = arow * FROW + cp * 12;   // elems; byte offset 16-aligned

  const int NT = k_iters;

  // ---- prologue: x(0..3); expand+write tiles 0,1; DMA B(0),B(1); drain.
  float2 x0    = *(const float2*)(xp + 0);
  float2 x1    = *(const float2*)(xp + 4);
  float2 x_use = *(const float2*)(xp + 8);    // x(2)
  float2 x_mid = *(const float2*)(xp + 12);   // x(3)
  float2 x_new = x_use;                       // filled at stage(0)

#pragma unroll
  for (int j = 0; j < FOPS; ++j) async16(bsrc[j],       S + 2 * FBUF + bdof[j]); // B(0)->p0
#pragma unroll
  for (int j = 0; j < FOPS; ++j) async16(bsrc[j] + FBK, S + 3 * FBUF + bdof[j]); // B(1)->p1
  {
    uint64_t e[6];
    expand2(x0, g0, inv_h, e); write_ev(S, awoff, e);           // A(0)->p0
    expand2(x1, g0, inv_h, e); write_ev(S + FBUF, awoff, e);    // A(1)->p1
  }
  asm volatile("s_waitcnt vmcnt(0) lgkmcnt(0)" ::: "memory");
  __builtin_amdgcn_s_barrier();
  __builtin_amdgcn_sched_barrier(0);

  // ---- main loop: iter t computes tile t (parity t&1), stages tile t+2.
  for (int t = 0; t < NT; ++t) {
    const int p = t & 1;
    const u16* Ab = S + p * FBUF;
    const u16* Bb = S + 2 * FBUF + p * FBUF;

    // expansion for tile t+2 (VALU; compiler interleaves with MFMA below)
    uint64_t e[6];
    const bool dostage = (t + 2 < NT);
    if (dostage) expand2(x_use, g0, inv_h, e);

    __builtin_amdgcn_s_setprio(1);
#pragma unroll
    for (int ks = 0; ks < 3; ++ks) {
      const int cc = (2 * ks + g8) * 8;
      short8 bf0 = *(const short8*)&Bb[(wn +      l31) * FROW + cc];
      short8 bf1 = *(const short8*)&Bb[(wn + 32 + l31) * FROW + cc];
#pragma unroll
      for (int m = 0; m < 4; ++m) {
        short8 af = *(const short8*)&Ab[(wm + m * 32 + l31) * FROW + cc];
        acc[m][0] = __builtin_amdgcn_mfma_f32_32x32x16_bf16(af, bf0, acc[m][0], 0, 0, 0);
        acc[m][1] = __builtin_amdgcn_mfma_f32_32x32x16_bf16(af, bf1, acc[m][1], 0, 0, 0);
      }
    }
    __builtin_amdgcn_s_setprio(0);

    __builtin_amdgcn_s_barrier();          // all waves done reading parity p
    __builtin_amdgcn_sched_barrier(0);

    if (dostage) {
      const int ko = (t + 2) * FBK;
      u16* Bd = S + 2 * FBUF + p * FBUF;   // just-freed B parity
#pragma unroll
      for (int j = 0; j < FOPS; ++j) async16(bsrc[j] + ko, Bd + bdof[j]);
      write_ev(S + p * FBUF, awoff, e);    // A(t+2) -> freed A parity
      if (t + 4 < NT) {
        x_new = *(const float2*)(xp + (size_t)(t + 4) * 4);
        // outstanding: B(t+1)x4 + x(t+3) + B(t+2)x4 + x(t+4) = 10;
        // vmcnt(5) certifies B(t+1), x(t+3); leaves t+2 batch in flight.
        asm volatile("s_waitcnt vmcnt(5) lgkmcnt(0)" ::: "memory");
      } else {
        // no x-load issued: certify B(t+1) and (if present) x(t+3).
        asm volatile("s_waitcnt vmcnt(4) lgkmcnt(0)" ::: "memory");
      }
    } else {
      asm volatile("s_waitcnt vmcnt(0) lgkmcnt(0)" ::: "memory");
    }
    __builtin_amdgcn_s_barrier();          // parity (t+1)&1 ready
    __builtin_amdgcn_sched_barrier(0);

    x_use = x_mid; x_mid = x_new;          // rotate x prefetch regs
  }

  // C/D map (m74/m101-verified): col=lane&31, row=(reg&3)+8*(reg>>2)+4*(lane>>5)
  float* op = (s == 0) ? out : part;
#pragma unroll
  for (int m = 0; m < 4; ++m)
#pragma unroll
    for (int n = 0; n < 2; ++n) {
      const int row0 = bm * 256 + wm + m * 32 + 4 * g8;
      const int col  = bn * 256 + wn + n * 32 + l31;
#pragma unroll
      for (int reg = 0; reg < 16; ++reg) {
        int row = row0 + (reg & 3) + 8 * (reg >> 2);
        op[(size_t)row * OUT_DIM + col] = acc[m][n][reg];
      }
    }
}

// out += part, float4-vectorized
__global__ __launch_bounds__(256) void reduce_kernel(
    float* __restrict__ out, const float* __restrict__ part)
{
  size_t i = (size_t)blockIdx.x * 256 + threadIdx.x;
  float4* o = (float4*)out;
  const float4* p = (const float4*)part;
  float4 a = o[i], b = p[i];
  a.x += b.x; a.y += b.y; a.z += b.z; a.w += b.w;
  o[i] = a;
}

extern "C" void kernel_launch(void* const* d_in, const int* in_sizes, int n_in,
                              void* d_out, int out_size, void* d_ws, size_t ws_size,
                              hipStream_t stream) {
  const float* x     = (const float*)d_in[0];
  const float* grid  = (const float*)d_in[1];
  const float* coeff = (const float*)d_in[2];
  const float* sb    = (const float*)d_in[3];
  const float* ss    = (const float*)d_in[4];
  float* out = (float*)d_out;

  u16* Wt = (u16*)d_ws;
  const size_t wt_bytes   = (size_t)OUT_DIM * KDIM * 2;     // 25.2 MB
  const size_t part_bytes = (size_t)TOKENS * OUT_DIM * 4;   // 33.6 MB

  pack_wt_kernel<<<(OUT_DIM * IN_DIM) / 256, 256, 0, stream>>>(coeff, sb, ss, Wt);

  if (ws_size >= wt_bytes + part_bytes) {
    // fused split-K=2: 256 blocks = 1/CU; K/split = 6144 = 128 tiles of 48
    float* part = (float*)((char*)d_ws + wt_bytes);
    gemm_fused2_kernel<<<128 * 2, 512, 0, stream>>>(x, grid, Wt, out, part, 128);
    reduce_kernel<<<(TOKENS * OUT_DIM / 4) / 256, 256, 0, stream>>>(out, part);
  } else {
    // no split: 128 blocks, full K (s==0 -> writes out directly)
    gemm_fused2_kernel<<<128, 512, 0, stream>>>(x, grid, Wt, out, nullptr, 256);
  }
}